// Round 1
// baseline (441.417 us; speedup 1.0000x reference)
//
#include <hip/hip_runtime.h>
#include <cmath>

// LoRAAttention, MI355X round 1.
// Design:
//  - LoRA q/k/v folded into W_qkv_eff = W_qkv + B_x@A_x (exact, rank-16).
//  - LoRA o folded into W_proj_eff = Wp + Bo@(Ao@Wp), b_eff = b + Bo@(Ao@b).
//  - bf16 MFMA 16x16x32 for QKV gemm, attention (S^T trick), proj gemm.
//  - Softmax without running max (logits provably ~|2| max), single 1/l at end.

#define DEVI __device__ __forceinline__

typedef float f32x4 __attribute__((ext_vector_type(4)));
typedef short s16x8 __attribute__((ext_vector_type(8)));
typedef __bf16 b16x8 __attribute__((ext_vector_type(8)));

static constexpr int MTOT = 16384;   // B*N
static constexpr int C = 768;
static constexpr int N3 = 2304;

DEVI unsigned short f2bf(float x) {
  unsigned int u = __builtin_bit_cast(unsigned int, x);
  return (unsigned short)((u + 0x7FFFu + ((u >> 16) & 1u)) >> 16);
}

DEVI f32x4 mfma16(s16x8 a, s16x8 b, f32x4 c) {
  return __builtin_amdgcn_mfma_f32_16x16x32_bf16(
      __builtin_bit_cast(b16x8, a), __builtin_bit_cast(b16x8, b), c, 0, 0, 0);
}

DEVI void async16(const void* g, void* l) {
  __builtin_amdgcn_global_load_lds(
      (__attribute__((address_space(1))) void*)g,
      (__attribute__((address_space(3))) void*)l, 16, 0, 0);
}

// ---------------- prep kernels ----------------

__global__ __launch_bounds__(256) void k_prep_x(const float* __restrict__ x,
                                                unsigned short* __restrict__ xb) {
  int idx = (blockIdx.x * 256 + threadIdx.x) * 4;
  float4 v = *(const float4*)(x + idx);
  uint2 p;
  p.x = (unsigned int)f2bf(v.x) | ((unsigned int)f2bf(v.y) << 16);
  p.y = (unsigned int)f2bf(v.z) | ((unsigned int)f2bf(v.w) << 16);
  *(uint2*)(xb + idx) = p;
}

__global__ __launch_bounds__(256) void k_prep_wqkv(
    const float* __restrict__ W, const float* __restrict__ Aq,
    const float* __restrict__ Bq, const float* __restrict__ Ak,
    const float* __restrict__ Bk, const float* __restrict__ Av,
    const float* __restrict__ Bv, unsigned short* __restrict__ out) {
  int idx = blockIdx.x * 256 + threadIdx.x;  // n*768 + c
  int n = idx / 768, c = idx - n * 768;
  int s = n / 768, co = n - s * 768;
  const float* A = (s == 0) ? Aq : (s == 1) ? Ak : Av;
  const float* Bm = (s == 0) ? Bq : (s == 1) ? Bk : Bv;
  float acc = W[idx];
#pragma unroll
  for (int r = 0; r < 16; ++r) acc += Bm[co * 16 + r] * A[r * 768 + c];
  out[idx] = f2bf(acc);
}

// M[r][j] = sum_c Ao[r][c] * Wp[c][j]
__global__ __launch_bounds__(256) void k_prep_M(const float* __restrict__ Ao,
                                                const float* __restrict__ Wp,
                                                float* __restrict__ M) {
  int r = blockIdx.x, t = threadIdx.x;
  float a0 = 0.f, a1 = 0.f, a2 = 0.f;
  for (int c = 0; c < 768; ++c) {
    float a = Ao[r * 768 + c];
    a0 += a * Wp[c * 768 + t];
    a1 += a * Wp[c * 768 + t + 256];
    a2 += a * Wp[c * 768 + t + 512];
  }
  M[r * 768 + t] = a0;
  M[r * 768 + t + 256] = a1;
  M[r * 768 + t + 512] = a2;
}

__global__ __launch_bounds__(256) void k_prep_wpe(const float* __restrict__ Wp,
                                                  const float* __restrict__ Bo,
                                                  const float* __restrict__ M,
                                                  unsigned short* __restrict__ out) {
  int idx = blockIdx.x * 256 + threadIdx.x;  // n*768 + j
  int n = idx / 768, j = idx - n * 768;
  float acc = Wp[idx];
#pragma unroll
  for (int r = 0; r < 16; ++r) acc += Bo[n * 16 + r] * M[r * 768 + j];
  out[idx] = f2bf(acc);
}

__global__ __launch_bounds__(256) void k_prep_beff(const float* __restrict__ bp,
                                                   const float* __restrict__ Ao,
                                                   const float* __restrict__ Bo,
                                                   float* __restrict__ beff) {
  __shared__ float bv[16];
  int t = threadIdx.x;
  if (t < 16) {
    float a0 = 0.f, a1 = 0.f, a2 = 0.f;
    for (int c = 0; c < 256; ++c) {
      a0 += Ao[t * 768 + c] * bp[c];
      a1 += Ao[t * 768 + c + 256] * bp[c + 256];
      a2 += Ao[t * 768 + c + 512] * bp[c + 512];
    }
    bv[t] = a0 + a1 + a2;
  }
  __syncthreads();
  int n = blockIdx.x * 256 + t;
  float acc = bp[n];
#pragma unroll
  for (int r = 0; r < 16; ++r) acc += Bo[n * 16 + r] * bv[r];
  beff[n] = acc;
}

// ---------------- QKV GEMM: [16384,768] x [2304,768]^T -> q/k/v bf16 [B,H,N,HD]

__global__ __launch_bounds__(256) void k_gemm_qkv(
    const unsigned short* __restrict__ A, const unsigned short* __restrict__ Bw,
    const float* __restrict__ bias, unsigned short* __restrict__ qb,
    unsigned short* __restrict__ kb, unsigned short* __restrict__ vb) {
  __shared__ short la[128 * 32];
  __shared__ short lb[128 * 32];
  const int t = threadIdx.x;
  const int w = t >> 6, l = t & 63;
  const int i = l & 15, qd = l >> 4;
  const int wm = w >> 1, wn = w & 1;
  const int mblk = blockIdx.x, nblk = blockIdx.y;

  const unsigned short* Ab = A + (size_t)(mblk * 128) * 768;
  const unsigned short* Bb = Bw + (size_t)(nblk * 128) * 768;
  const int sr = l >> 2;        // 0..15
  const int sc = (l & 3) * 8;   // 0,8,16,24

  f32x4 acc[4][4] = {};

  for (int kb_ = 0; kb_ < 24; ++kb_) {
    const int k0 = kb_ * 32;
#pragma unroll
    for (int j = 0; j < 2; ++j) {
      const int row = w * 32 + j * 16 + sr;
      async16(Ab + row * 768 + k0 + sc, &la[(w * 32 + j * 16) * 32]);
      async16(Bb + row * 768 + k0 + sc, &lb[(w * 32 + j * 16) * 32]);
    }
    __syncthreads();
    s16x8 af[4], bf[4];
#pragma unroll
    for (int mi = 0; mi < 4; ++mi)
      af[mi] = *(const s16x8*)&la[(wm * 64 + mi * 16 + i) * 32 + qd * 8];
#pragma unroll
    for (int ni = 0; ni < 4; ++ni)
      bf[ni] = *(const s16x8*)&lb[(wn * 64 + ni * 16 + i) * 32 + qd * 8];
#pragma unroll
    for (int mi = 0; mi < 4; ++mi)
#pragma unroll
      for (int ni = 0; ni < 4; ++ni)
        acc[mi][ni] = mfma16(af[mi], bf[ni], acc[mi][ni]);
    __syncthreads();
  }

#pragma unroll
  for (int ni = 0; ni < 4; ++ni) {
    const int n = nblk * 128 + wn * 64 + ni * 16 + i;
    const int s = n / 768;
    const int nrel = n - s * 768;
    const int h = nrel >> 6, d = nrel & 63;
    unsigned short* dst = (s == 0) ? qb : (s == 1) ? kb : vb;
    const float bvv = bias[n];
#pragma unroll
    for (int mi = 0; mi < 4; ++mi) {
#pragma unroll
      for (int r = 0; r < 4; ++r) {
        const int m = mblk * 128 + wm * 64 + mi * 16 + qd * 4 + r;
        const int b = m >> 10, pos = m & 1023;
        dst[(size_t)((b * 12 + h) * 1024 + pos) * 64 + d] =
            f2bf(acc[mi][ni][r] + bvv);
      }
    }
  }
}

// ---------------- flash attention (no-max softmax, S^T trick) ----------------
// grid: (8 q-tiles, 192 bh), 256 threads. Q-tile 128 rows, KV-tile 64.

__global__ __launch_bounds__(256) void k_attn(const unsigned short* __restrict__ qg,
                                              const unsigned short* __restrict__ kg,
                                              const unsigned short* __restrict__ vg,
                                              unsigned short* __restrict__ og) {
  __shared__ short q_lds[128 * 72];
  __shared__ short k_lds[64 * 72];
  __shared__ short vt_lds[64 * 72];
  __shared__ short p_lds[128 * 72];

  const int t = threadIdx.x;
  const int w = t >> 6, l = t & 63;
  const int i = l & 15, qd = l >> 4;
  const int qblk = blockIdx.x;  // 0..7
  const int bh = blockIdx.y;    // 0..191
  const int h = bh % 12, b = bh / 12;

  const unsigned short* Qg = qg + (size_t)(bh * 1024 + qblk * 128) * 64;
  const unsigned short* Kg = kg + (size_t)bh * 1024 * 64;
  const unsigned short* Vg = vg + (size_t)bh * 1024 * 64;

  // stage Q tile [128][64] -> q_lds [128][72]
#pragma unroll
  for (int it = 0; it < 4; ++it) {
    int c = t + it * 256;
    int pos = c >> 3, d0 = (c & 7) * 8;
    *(s16x8*)&q_lds[pos * 72 + d0] = *(const s16x8*)(Qg + pos * 64 + d0);
  }
  __syncthreads();

  // preload Q B-frags: B[k=d][n=qrow]
  s16x8 qf[2][2];  // [nq][k0]
#pragma unroll
  for (int nq = 0; nq < 2; ++nq)
#pragma unroll
    for (int k0 = 0; k0 < 2; ++k0)
      qf[nq][k0] =
          *(const s16x8*)&q_lds[(w * 32 + nq * 16 + i) * 72 + k0 * 32 + qd * 8];

  f32x4 oacc[2][4] = {};  // [mq][nd]
  float lsum[2] = {0.f, 0.f};
  const float c1 = 0.18033688011112042f;  // SCALE * log2(e)

  for (int tkv = 0; tkv < 16; ++tkv) {
    __syncthreads();  // staging region reuse guard
    // stage K [64][64] -> k_lds [64][72]
#pragma unroll
    for (int it = 0; it < 2; ++it) {
      int c = t + it * 256;
      int pos = c >> 3, d0 = (c & 7) * 8;
      *(s16x8*)&k_lds[pos * 72 + d0] =
          *(const s16x8*)(Kg + (size_t)(tkv * 64 + pos) * 64 + d0);
    }
    // stage V transposed: vt[d][pos]
    {
      int d = t & 63, pc = t >> 6;
#pragma unroll
      for (int it = 0; it < 2; ++it) {
        int pos0 = pc * 8 + it * 32;
        s16x8 pk;
#pragma unroll
        for (int j = 0; j < 8; ++j)
          pk[j] = (short)Vg[(size_t)(tkv * 64 + pos0 + j) * 64 + d];
        *(s16x8*)&vt_lds[d * 72 + pos0] = pk;
      }
    }
    __syncthreads();

    // GEMM1: S^T[pos][qrow] = K * Q^T
    f32x4 st[4][2] = {};
#pragma unroll
    for (int k0 = 0; k0 < 2; ++k0) {
      s16x8 kf[4];
#pragma unroll
      for (int mi = 0; mi < 4; ++mi)
        kf[mi] = *(const s16x8*)&k_lds[(mi * 16 + i) * 72 + k0 * 32 + qd * 8];
#pragma unroll
      for (int mi = 0; mi < 4; ++mi)
#pragma unroll
        for (int nq = 0; nq < 2; ++nq)
          st[mi][nq] = mfma16(kf[mi], qf[nq][k0], st[mi][nq]);
    }

    // softmax exp (no max), accumulate l, write P to p_lds[qrow][pos] (bf16)
#pragma unroll
    for (int nq = 0; nq < 2; ++nq) {
#pragma unroll
      for (int mi = 0; mi < 4; ++mi) {
        float p0 = exp2f(st[mi][nq][0] * c1);
        float p1 = exp2f(st[mi][nq][1] * c1);
        float p2 = exp2f(st[mi][nq][2] * c1);
        float p3 = exp2f(st[mi][nq][3] * c1);
        lsum[nq] += (p0 + p1) + (p2 + p3);
        uint2 pk;
        pk.x = (unsigned int)f2bf(p0) | ((unsigned int)f2bf(p1) << 16);
        pk.y = (unsigned int)f2bf(p2) | ((unsigned int)f2bf(p3) << 16);
        *(uint2*)&p_lds[(w * 32 + nq * 16 + i) * 72 + mi * 16 + qd * 4] = pk;
      }
    }

    // GEMM2: O[qrow][d] += P[qrow][pos] * V[pos][d]   (wave-private p_lds rows)
#pragma unroll
    for (int ks = 0; ks < 2; ++ks) {
      s16x8 pf[2], vf[4];
#pragma unroll
      for (int mq = 0; mq < 2; ++mq)
        pf[mq] =
            *(const s16x8*)&p_lds[(w * 32 + mq * 16 + i) * 72 + ks * 32 + qd * 8];
#pragma unroll
      for (int nd = 0; nd < 4; ++nd)
        vf[nd] = *(const s16x8*)&vt_lds[(nd * 16 + i) * 72 + ks * 32 + qd * 8];
#pragma unroll
      for (int mq = 0; mq < 2; ++mq)
#pragma unroll
        for (int nd = 0; nd < 4; ++nd)
          oacc[mq][nd] = mfma16(pf[mq], vf[nd], oacc[mq][nd]);
    }
  }

  // reduce l across the 4 quads (each qrow replicated over quads)
#pragma unroll
  for (int nq = 0; nq < 2; ++nq) {
    lsum[nq] += __shfl_xor(lsum[nq], 16);
    lsum[nq] += __shfl_xor(lsum[nq], 32);
  }
  // redistribute to C-layout rows: row-local = mq*16 + qd*4 + r held by lane (qd*4+r)
  float linv[2][4];
#pragma unroll
  for (int mq = 0; mq < 2; ++mq)
#pragma unroll
    for (int r = 0; r < 4; ++r)
      linv[mq][r] = 1.0f / __shfl(lsum[mq], qd * 4 + r);

  const int orow0 = qblk * 128 + w * 32;
#pragma unroll
  for (int mq = 0; mq < 2; ++mq)
#pragma unroll
    for (int nd = 0; nd < 4; ++nd)
#pragma unroll
      for (int r = 0; r < 4; ++r) {
        const int pos = orow0 + mq * 16 + qd * 4 + r;
        const int d = nd * 16 + i;
        og[(size_t)(b * 1024 + pos) * 768 + h * 64 + d] =
            f2bf(oacc[mq][nd][r] * linv[mq][r]);
      }
}

// ---------------- proj GEMM: [16384,768] x [768,768]^T + b_eff -> f32 out ----

__global__ __launch_bounds__(256) void k_gemm_proj(
    const unsigned short* __restrict__ A, const unsigned short* __restrict__ Bw,
    const float* __restrict__ bias, float* __restrict__ out) {
  __shared__ short la[128 * 32];
  __shared__ short lb[128 * 32];
  const int t = threadIdx.x;
  const int w = t >> 6, l = t & 63;
  const int i = l & 15, qd = l >> 4;
  const int wm = w >> 1, wn = w & 1;
  const int mblk = blockIdx.x, nblk = blockIdx.y;

  const unsigned short* Ab = A + (size_t)(mblk * 128) * 768;
  const unsigned short* Bb = Bw + (size_t)(nblk * 128) * 768;
  const int sr = l >> 2;
  const int sc = (l & 3) * 8;

  f32x4 acc[4][4] = {};

  for (int kb_ = 0; kb_ < 24; ++kb_) {
    const int k0 = kb_ * 32;
#pragma unroll
    for (int j = 0; j < 2; ++j) {
      const int row = w * 32 + j * 16 + sr;
      async16(Ab + row * 768 + k0 + sc, &la[(w * 32 + j * 16) * 32]);
      async16(Bb + row * 768 + k0 + sc, &lb[(w * 32 + j * 16) * 32]);
    }
    __syncthreads();
    s16x8 af[4], bf[4];
#pragma unroll
    for (int mi = 0; mi < 4; ++mi)
      af[mi] = *(const s16x8*)&la[(wm * 64 + mi * 16 + i) * 32 + qd * 8];
#pragma unroll
    for (int ni = 0; ni < 4; ++ni)
      bf[ni] = *(const s16x8*)&lb[(wn * 64 + ni * 16 + i) * 32 + qd * 8];
#pragma unroll
    for (int mi = 0; mi < 4; ++mi)
#pragma unroll
      for (int ni = 0; ni < 4; ++ni)
        acc[mi][ni] = mfma16(af[mi], bf[ni], acc[mi][ni]);
    __syncthreads();
  }

#pragma unroll
  for (int ni = 0; ni < 4; ++ni) {
    const int n = nblk * 128 + wn * 64 + ni * 16 + i;
    const float bvv = bias[n];
#pragma unroll
    for (int mi = 0; mi < 4; ++mi) {
#pragma unroll
      for (int r = 0; r < 4; ++r) {
        const int m = mblk * 128 + wm * 64 + mi * 16 + qd * 4 + r;
        out[(size_t)m * 768 + n] = acc[mi][ni][r] + bvv;
      }
    }
  }
}

// ---------------- host ----------------

extern "C" void kernel_launch(void* const* d_in, const int* in_sizes, int n_in,
                              void* d_out, int out_size, void* d_ws, size_t ws_size,
                              hipStream_t stream) {
  const float* x = (const float*)d_in[0];
  const float* Wqkv = (const float*)d_in[1];
  const float* bqkv = (const float*)d_in[2];
  const float* Wp = (const float*)d_in[3];
  const float* bp = (const float*)d_in[4];
  const float* Aq = (const float*)d_in[5];
  const float* Bq = (const float*)d_in[6];
  const float* Ak = (const float*)d_in[7];
  const float* Bk = (const float*)d_in[8];
  const float* Av = (const float*)d_in[9];
  const float* Bv = (const float*)d_in[10];
  const float* Ao = (const float*)d_in[11];
  const float* Bo = (const float*)d_in[12];
  float* out = (float*)d_out;

  // workspace layout (bf16 buffers as ushort)
  unsigned short* xb = (unsigned short*)d_ws;         // 16384*768
  unsigned short* wqkvb = xb + (size_t)MTOT * C;      // 2304*768
  unsigned short* wpeb = wqkvb + (size_t)N3 * C;      // 768*768
  unsigned short* qb = wpeb + (size_t)C * C;          // 192*1024*64
  unsigned short* kb = qb + (size_t)MTOT * C;
  unsigned short* vb = kb + (size_t)MTOT * C;
  float* Mbuf = (float*)(vb + (size_t)MTOT * C);      // 16*768
  float* beff = Mbuf + 16 * 768;                      // 768
  unsigned short* ob = xb;  // alias: xb dead after k_gemm_qkv

  k_prep_x<<<12288, 256, 0, stream>>>(x, xb);
  k_prep_wqkv<<<6912, 256, 0, stream>>>(Wqkv, Aq, Bq, Ak, Bk, Av, Bv, wqkvb);
  k_prep_M<<<16, 256, 0, stream>>>(Ao, Wp, Mbuf);
  k_prep_wpe<<<2304, 256, 0, stream>>>(Wp, Bo, Mbuf, wpeb);
  k_prep_beff<<<3, 256, 0, stream>>>(bp, Ao, Bo, beff);

  k_gemm_qkv<<<dim3(128, 18), 256, 0, stream>>>(xb, wqkvb, bqkv, qb, kb, vb);
  k_attn<<<dim3(8, 192), 256, 0, stream>>>(qb, kb, vb, ob);
  k_gemm_proj<<<dim3(128, 6), 256, 0, stream>>>(ob, wpeb, beff, out);
}

// Round 2
// 437.051 us; speedup vs baseline: 1.0100x; 1.0100x over previous
//
#include <hip/hip_runtime.h>
#include <cmath>

// LoRAAttention, MI355X round 2.
//  - LoRA folded into effective weights (exact).
//  - QKV epilogue: q pre-scaled by SCALE*log2e, V stored transposed [bh][d][pos].
//  - Attention: 256-row Q tiles, Q frags direct from global, double-buffered
//    async (global_load_lds) K/V^T staging with XOR-swizzled LDS, no-max
//    softmax with truncating P pack (v_perm) + consistent l-sum.

#define DEVI __device__ __forceinline__

typedef float f32x4 __attribute__((ext_vector_type(4)));
typedef short s16x8 __attribute__((ext_vector_type(8)));
typedef __bf16 b16x8 __attribute__((ext_vector_type(8)));

static constexpr int MTOT = 16384;   // B*N
static constexpr int C = 768;
static constexpr int N3 = 2304;

DEVI unsigned short f2bf(float x) {
  unsigned int u = __builtin_bit_cast(unsigned int, x);
  return (unsigned short)((u + 0x7FFFu + ((u >> 16) & 1u)) >> 16);
}

DEVI f32x4 mfma16(s16x8 a, s16x8 b, f32x4 c) {
  return __builtin_amdgcn_mfma_f32_16x16x32_bf16(
      __builtin_bit_cast(b16x8, a), __builtin_bit_cast(b16x8, b), c, 0, 0, 0);
}

DEVI void async16(const void* g, void* l) {
  __builtin_amdgcn_global_load_lds(
      (__attribute__((address_space(1))) void*)g,
      (__attribute__((address_space(3))) void*)l, 16, 0, 0);
}

// ---------------- prep kernels ----------------

__global__ __launch_bounds__(256) void k_prep_x(const float* __restrict__ x,
                                                unsigned short* __restrict__ xb) {
  int idx = (blockIdx.x * 256 + threadIdx.x) * 4;
  float4 v = *(const float4*)(x + idx);
  uint2 p;
  p.x = (unsigned int)f2bf(v.x) | ((unsigned int)f2bf(v.y) << 16);
  p.y = (unsigned int)f2bf(v.z) | ((unsigned int)f2bf(v.w) << 16);
  *(uint2*)(xb + idx) = p;
}

__global__ __launch_bounds__(256) void k_prep_wqkv(
    const float* __restrict__ W, const float* __restrict__ Aq,
    const float* __restrict__ Bq, const float* __restrict__ Ak,
    const float* __restrict__ Bk, const float* __restrict__ Av,
    const float* __restrict__ Bv, unsigned short* __restrict__ out) {
  int idx = blockIdx.x * 256 + threadIdx.x;  // n*768 + c
  int n = idx / 768, c = idx - n * 768;
  int s = n / 768, co = n - s * 768;
  const float* A = (s == 0) ? Aq : (s == 1) ? Ak : Av;
  const float* Bm = (s == 0) ? Bq : (s == 1) ? Bk : Bv;
  float acc = W[idx];
#pragma unroll
  for (int r = 0; r < 16; ++r) acc += Bm[co * 16 + r] * A[r * 768 + c];
  out[idx] = f2bf(acc);
}

// M[r][j] = sum_c Ao[r][c] * Wp[c][j]
__global__ __launch_bounds__(256) void k_prep_M(const float* __restrict__ Ao,
                                                const float* __restrict__ Wp,
                                                float* __restrict__ M) {
  int r = blockIdx.x, t = threadIdx.x;
  float a0 = 0.f, a1 = 0.f, a2 = 0.f;
  for (int c = 0; c < 768; ++c) {
    float a = Ao[r * 768 + c];
    a0 += a * Wp[c * 768 + t];
    a1 += a * Wp[c * 768 + t + 256];
    a2 += a * Wp[c * 768 + t + 512];
  }
  M[r * 768 + t] = a0;
  M[r * 768 + t + 256] = a1;
  M[r * 768 + t + 512] = a2;
}

__global__ __launch_bounds__(256) void k_prep_wpe(const float* __restrict__ Wp,
                                                  const float* __restrict__ Bo,
                                                  const float* __restrict__ M,
                                                  unsigned short* __restrict__ out) {
  int idx = blockIdx.x * 256 + threadIdx.x;  // n*768 + j
  int n = idx / 768, j = idx - n * 768;
  float acc = Wp[idx];
#pragma unroll
  for (int r = 0; r < 16; ++r) acc += Bo[n * 16 + r] * M[r * 768 + j];
  out[idx] = f2bf(acc);
}

__global__ __launch_bounds__(256) void k_prep_beff(const float* __restrict__ bp,
                                                   const float* __restrict__ Ao,
                                                   const float* __restrict__ Bo,
                                                   float* __restrict__ beff) {
  __shared__ float bv[16];
  int t = threadIdx.x;
  if (t < 16) {
    float a0 = 0.f, a1 = 0.f, a2 = 0.f;
    for (int c = 0; c < 256; ++c) {
      a0 += Ao[t * 768 + c] * bp[c];
      a1 += Ao[t * 768 + c + 256] * bp[c + 256];
      a2 += Ao[t * 768 + c + 512] * bp[c + 512];
    }
    bv[t] = a0 + a1 + a2;
  }
  __syncthreads();
  int n = blockIdx.x * 256 + t;
  float acc = bp[n];
#pragma unroll
  for (int r = 0; r < 16; ++r) acc += Bo[n * 16 + r] * bv[r];
  beff[n] = acc;
}

// ---------------- QKV GEMM: [16384,768] x [2304,768]^T -> q/k/vt bf16 --------
// q: [bh][pos][64], pre-scaled by SCALE*log2e.  k: [bh][pos][64].
// vt: [bh][64][1024] (transposed per head), packed 8B stores.

__global__ __launch_bounds__(256) void k_gemm_qkv(
    const unsigned short* __restrict__ A, const unsigned short* __restrict__ Bw,
    const float* __restrict__ bias, unsigned short* __restrict__ qb,
    unsigned short* __restrict__ kb, unsigned short* __restrict__ vtb) {
  __shared__ short la[128 * 32];
  __shared__ short lb[128 * 32];
  const int t = threadIdx.x;
  const int w = t >> 6, l = t & 63;
  const int i = l & 15, qd = l >> 4;
  const int wm = w >> 1, wn = w & 1;
  const int mblk = blockIdx.x, nblk = blockIdx.y;

  const unsigned short* Ab = A + (size_t)(mblk * 128) * 768;
  const unsigned short* Bb = Bw + (size_t)(nblk * 128) * 768;
  const int sr = l >> 2;        // 0..15
  const int sc = (l & 3) * 8;   // 0,8,16,24

  f32x4 acc[4][4] = {};

  for (int kb_ = 0; kb_ < 24; ++kb_) {
    const int k0 = kb_ * 32;
#pragma unroll
    for (int j = 0; j < 2; ++j) {
      const int row = w * 32 + j * 16 + sr;
      async16(Ab + row * 768 + k0 + sc, &la[(w * 32 + j * 16) * 32]);
      async16(Bb + row * 768 + k0 + sc, &lb[(w * 32 + j * 16) * 32]);
    }
    __syncthreads();
    s16x8 af[4], bf[4];
#pragma unroll
    for (int mi = 0; mi < 4; ++mi)
      af[mi] = *(const s16x8*)&la[(wm * 64 + mi * 16 + i) * 32 + qd * 8];
#pragma unroll
    for (int ni = 0; ni < 4; ++ni)
      bf[ni] = *(const s16x8*)&lb[(wn * 64 + ni * 16 + i) * 32 + qd * 8];
#pragma unroll
    for (int mi = 0; mi < 4; ++mi)
#pragma unroll
      for (int ni = 0; ni < 4; ++ni)
        acc[mi][ni] = mfma16(af[mi], bf[ni], acc[mi][ni]);
    __syncthreads();
  }

  const float c1 = 0.18033688011112042f;  // SCALE * log2(e)
#pragma unroll
  for (int ni = 0; ni < 4; ++ni) {
    const int n = nblk * 128 + wn * 64 + ni * 16 + i;
    const int s = n / 768;
    const int nrel = n - s * 768;
    const int h = nrel >> 6, d = nrel & 63;
    const float bvv = bias[n];
    if (s == 2) {
      // V: transposed, packed 4x bf16 (r -> consecutive pos)
#pragma unroll
      for (int mi = 0; mi < 4; ++mi) {
        const int m0 = mblk * 128 + wm * 64 + mi * 16 + qd * 4;
        const int b = m0 >> 10, pos0 = m0 & 1023;
        uint2 pk;
        pk.x = (unsigned int)f2bf(acc[mi][ni][0] + bvv) |
               ((unsigned int)f2bf(acc[mi][ni][1] + bvv) << 16);
        pk.y = (unsigned int)f2bf(acc[mi][ni][2] + bvv) |
               ((unsigned int)f2bf(acc[mi][ni][3] + bvv) << 16);
        *(uint2*)&vtb[(size_t)((b * 12 + h) * 64 + d) * 1024 + pos0] = pk;
      }
    } else {
      unsigned short* dst = (s == 0) ? qb : kb;
      const float scl = (s == 0) ? c1 : 1.0f;
#pragma unroll
      for (int mi = 0; mi < 4; ++mi) {
#pragma unroll
        for (int r = 0; r < 4; ++r) {
          const int m = mblk * 128 + wm * 64 + mi * 16 + qd * 4 + r;
          const int b = m >> 10, pos = m & 1023;
          dst[(size_t)((b * 12 + h) * 1024 + pos) * 64 + d] =
              f2bf((acc[mi][ni][r] + bvv) * scl);
        }
      }
    }
  }
}

// ---------------- flash attention round 2 ----------------
// grid: (4 q-tiles of 256 rows, 192 bh), 256 threads (4 waves x 64 q-rows).
// KV-tile 64, double-buffered async staging, XOR-swizzled K/Vt LDS.

__global__ __launch_bounds__(256, 2) void k_attn(
    const unsigned short* __restrict__ qg, const unsigned short* __restrict__ kg,
    const unsigned short* __restrict__ vtg, unsigned short* __restrict__ og) {
  __shared__ short k_lds[2][64 * 64];
  __shared__ short vt_lds[2][64 * 64];
  __shared__ short p_lds[256 * 72];

  const int t = threadIdx.x;
  const int w = t >> 6, l = t & 63;
  const int i = l & 15, qd = l >> 4;
  const int qblk = blockIdx.x;  // 0..3
  const int bh = blockIdx.y;    // 0..191
  const int h = bh % 12, b = bh / 12;

  const unsigned short* Qg = qg + (size_t)(bh * 1024 + qblk * 256) * 64;
  const unsigned short* Kg = kg + (size_t)bh * 1024 * 64;
  const unsigned short* Vtg = vtg + (size_t)bh * 64 * 1024;

  // staging lane mapping (lane -> 16B LDS chunk, XOR swizzle on global side)
  const int srl = l >> 3;            // row-local 0..7
  const int sgc = (l & 7) ^ srl;     // swizzled global chunk 0..7

  // Q B-fragments direct from global: qf[nq][k0] = Q[w*64+nq*16+i][k0*32+qd*8..]
  s16x8 qf[4][2];
#pragma unroll
  for (int nq = 0; nq < 4; ++nq)
#pragma unroll
    for (int k0 = 0; k0 < 2; ++k0)
      qf[nq][k0] =
          *(const s16x8*)(Qg + (w * 64 + nq * 16 + i) * 64 + k0 * 32 + qd * 8);

  // stage K and Vt tile tkv into buffer bufn (async, no wait)
  auto stage = [&](int bufn, int tkv) {
#pragma unroll
    for (int it = 0; it < 2; ++it) {
      const int rbase = it * 32 + w * 8;
      async16(Kg + (size_t)(tkv * 64 + rbase + srl) * 64 + sgc * 8,
              &k_lds[bufn][rbase * 64]);
      async16(Vtg + (size_t)(rbase + srl) * 1024 + tkv * 64 + sgc * 8,
              &vt_lds[bufn][rbase * 64]);
    }
  };

  stage(0, 0);

  f32x4 oacc[4][4] = {};  // [mq][nd]
  float lsum[4] = {0.f, 0.f, 0.f, 0.f};
  const int swz = i & 7;

  for (int tkv = 0; tkv < 16; ++tkv) {
    const int buf = tkv & 1;
    __syncthreads();  // staging for buf complete (vmcnt drained before barrier)
    if (tkv < 15) stage(buf ^ 1, tkv + 1);

    // GEMM1: S^T[pos][qrow] = K * Q^T
    f32x4 st[4][4] = {};
#pragma unroll
    for (int k0 = 0; k0 < 2; ++k0) {
      s16x8 kf[4];
#pragma unroll
      for (int mi = 0; mi < 4; ++mi)
        kf[mi] = *(const s16x8*)&k_lds[buf][(mi * 16 + i) * 64 +
                                            (((k0 * 4 + qd) ^ swz) * 8)];
#pragma unroll
      for (int mi = 0; mi < 4; ++mi)
#pragma unroll
        for (int nq = 0; nq < 4; ++nq)
          st[mi][nq] = mfma16(kf[mi], qf[nq][k0], st[mi][nq]);
    }

    // exp2 (pre-scaled logits), truncating pack, consistent l-sum
#pragma unroll
    for (int nq = 0; nq < 4; ++nq) {
#pragma unroll
      for (int mi = 0; mi < 4; ++mi) {
        unsigned int u0 = __builtin_bit_cast(unsigned int, exp2f(st[mi][nq][0]));
        unsigned int u1 = __builtin_bit_cast(unsigned int, exp2f(st[mi][nq][1]));
        unsigned int u2 = __builtin_bit_cast(unsigned int, exp2f(st[mi][nq][2]));
        unsigned int u3 = __builtin_bit_cast(unsigned int, exp2f(st[mi][nq][3]));
        lsum[nq] += __builtin_bit_cast(float, u0 & 0xFFFF0000u) +
                    __builtin_bit_cast(float, u1 & 0xFFFF0000u) +
                    __builtin_bit_cast(float, u2 & 0xFFFF0000u) +
                    __builtin_bit_cast(float, u3 & 0xFFFF0000u);
        uint2 pk;
        pk.x = __builtin_amdgcn_perm(u1, u0, 0x07060302u);
        pk.y = __builtin_amdgcn_perm(u3, u2, 0x07060302u);
        *(uint2*)&p_lds[(w * 64 + nq * 16 + i) * 72 + mi * 16 + qd * 4] = pk;
      }
    }

    // GEMM2: O[qrow][d] += P[qrow][pos] * V[pos][d]  (wave-private P rows)
#pragma unroll
    for (int ks = 0; ks < 2; ++ks) {
      s16x8 pf[4], vf[4];
#pragma unroll
      for (int mq = 0; mq < 4; ++mq)
        pf[mq] =
            *(const s16x8*)&p_lds[(w * 64 + mq * 16 + i) * 72 + ks * 32 + qd * 8];
#pragma unroll
      for (int nd = 0; nd < 4; ++nd)
        vf[nd] = *(const s16x8*)&vt_lds[buf][(nd * 16 + i) * 64 +
                                             (((ks * 4 + qd) ^ swz) * 8)];
#pragma unroll
      for (int mq = 0; mq < 4; ++mq)
#pragma unroll
        for (int nd = 0; nd < 4; ++nd)
          oacc[mq][nd] = mfma16(pf[mq], vf[nd], oacc[mq][nd]);
    }
  }

  // reduce l across the 4 quads (each qrow's partials spread over quads)
#pragma unroll
  for (int nq = 0; nq < 4; ++nq) {
    lsum[nq] += __shfl_xor(lsum[nq], 16);
    lsum[nq] += __shfl_xor(lsum[nq], 32);
  }
  float linv[4][4];
#pragma unroll
  for (int mq = 0; mq < 4; ++mq)
#pragma unroll
    for (int r = 0; r < 4; ++r)
      linv[mq][r] = 1.0f / __shfl(lsum[mq], qd * 4 + r);

  const int orow0 = qblk * 256 + w * 64;
#pragma unroll
  for (int mq = 0; mq < 4; ++mq)
#pragma unroll
    for (int nd = 0; nd < 4; ++nd)
#pragma unroll
      for (int r = 0; r < 4; ++r) {
        const int pos = orow0 + mq * 16 + qd * 4 + r;
        const int d = nd * 16 + i;
        og[(size_t)(b * 1024 + pos) * 768 + h * 64 + d] =
            f2bf(oacc[mq][nd][r] * linv[mq][r]);
      }
}

// ---------------- proj GEMM: [16384,768] x [768,768]^T + b_eff -> f32 out ----

__global__ __launch_bounds__(256) void k_gemm_proj(
    const unsigned short* __restrict__ A, const unsigned short* __restrict__ Bw,
    const float* __restrict__ bias, float* __restrict__ out) {
  __shared__ short la[128 * 32];
  __shared__ short lb[128 * 32];
  const int t = threadIdx.x;
  const int w = t >> 6, l = t & 63;
  const int i = l & 15, qd = l >> 4;
  const int wm = w >> 1, wn = w & 1;
  const int mblk = blockIdx.x, nblk = blockIdx.y;

  const unsigned short* Ab = A + (size_t)(mblk * 128) * 768;
  const unsigned short* Bb = Bw + (size_t)(nblk * 128) * 768;
  const int sr = l >> 2;
  const int sc = (l & 3) * 8;

  f32x4 acc[4][4] = {};

  for (int kb_ = 0; kb_ < 24; ++kb_) {
    const int k0 = kb_ * 32;
#pragma unroll
    for (int j = 0; j < 2; ++j) {
      const int row = w * 32 + j * 16 + sr;
      async16(Ab + row * 768 + k0 + sc, &la[(w * 32 + j * 16) * 32]);
      async16(Bb + row * 768 + k0 + sc, &lb[(w * 32 + j * 16) * 32]);
    }
    __syncthreads();
    s16x8 af[4], bf[4];
#pragma unroll
    for (int mi = 0; mi < 4; ++mi)
      af[mi] = *(const s16x8*)&la[(wm * 64 + mi * 16 + i) * 32 + qd * 8];
#pragma unroll
    for (int ni = 0; ni < 4; ++ni)
      bf[ni] = *(const s16x8*)&lb[(wn * 64 + ni * 16 + i) * 32 + qd * 8];
#pragma unroll
    for (int mi = 0; mi < 4; ++mi)
#pragma unroll
      for (int ni = 0; ni < 4; ++ni)
        acc[mi][ni] = mfma16(af[mi], bf[ni], acc[mi][ni]);
    __syncthreads();
  }

#pragma unroll
  for (int ni = 0; ni < 4; ++ni) {
    const int n = nblk * 128 + wn * 64 + ni * 16 + i;
    const float bvv = bias[n];
#pragma unroll
    for (int mi = 0; mi < 4; ++mi) {
#pragma unroll
      for (int r = 0; r < 4; ++r) {
        const int m = mblk * 128 + wm * 64 + mi * 16 + qd * 4 + r;
        out[(size_t)m * 768 + n] = acc[mi][ni][r] + bvv;
      }
    }
  }
}

// ---------------- host ----------------

extern "C" void kernel_launch(void* const* d_in, const int* in_sizes, int n_in,
                              void* d_out, int out_size, void* d_ws, size_t ws_size,
                              hipStream_t stream) {
  const float* x = (const float*)d_in[0];
  const float* Wqkv = (const float*)d_in[1];
  const float* bqkv = (const float*)d_in[2];
  const float* Wp = (const float*)d_in[3];
  const float* bp = (const float*)d_in[4];
  const float* Aq = (const float*)d_in[5];
  const float* Bq = (const float*)d_in[6];
  const float* Ak = (const float*)d_in[7];
  const float* Bk = (const float*)d_in[8];
  const float* Av = (const float*)d_in[9];
  const float* Bv = (const float*)d_in[10];
  const float* Ao = (const float*)d_in[11];
  const float* Bo = (const float*)d_in[12];
  float* out = (float*)d_out;

  unsigned short* xb = (unsigned short*)d_ws;         // 16384*768
  unsigned short* wqkvb = xb + (size_t)MTOT * C;      // 2304*768
  unsigned short* wpeb = wqkvb + (size_t)N3 * C;      // 768*768
  unsigned short* qb = wpeb + (size_t)C * C;          // 192*1024*64
  unsigned short* kb = qb + (size_t)MTOT * C;
  unsigned short* vtb = kb + (size_t)MTOT * C;        // 192*64*1024 (transposed)
  float* Mbuf = (float*)(vtb + (size_t)MTOT * C);     // 16*768
  float* beff = Mbuf + 16 * 768;                      // 768
  unsigned short* ob = xb;  // alias: xb dead after k_gemm_qkv

  k_prep_x<<<12288, 256, 0, stream>>>(x, xb);
  k_prep_wqkv<<<6912, 256, 0, stream>>>(Wqkv, Aq, Bq, Ak, Bk, Av, Bv, wqkvb);
  k_prep_M<<<16, 256, 0, stream>>>(Ao, Wp, Mbuf);
  k_prep_wpe<<<2304, 256, 0, stream>>>(Wp, Bo, Mbuf, wpeb);
  k_prep_beff<<<3, 256, 0, stream>>>(bp, Ao, Bo, beff);

  k_gemm_qkv<<<dim3(128, 18), 256, 0, stream>>>(xb, wqkvb, bqkv, qb, kb, vtb);
  k_attn<<<dim3(4, 192), 256, 0, stream>>>(qb, kb, vtb, ob);
  k_gemm_proj<<<dim3(128, 6), 256, 0, stream>>>(ob, wpeb, beff, out);
}

// Round 3
// 400.199 us; speedup vs baseline: 1.1030x; 1.0921x over previous
//
#include <hip/hip_runtime.h>
#include <cmath>

// LoRAAttention, MI355X round 3.
//  - LoRA folded into effective weights (exact).
//  - QKV epilogue: q pre-scaled by SCALE*log2e, V stored transposed [bh][d][pos].
//  - Attention: 128-row Q tiles, wave=32 qrows; P stays in registers via the
//    C-layout == half-K A-layout identity; l-sum via ones-column MFMA (lands in
//    the same lane/reg layout as O, no shuffles); native v_exp_f32; async
//    double-buffered K/V^T staging.

#define DEVI __device__ __forceinline__

typedef float f32x4 __attribute__((ext_vector_type(4)));
typedef short s16x8 __attribute__((ext_vector_type(8)));
typedef __bf16 b16x8 __attribute__((ext_vector_type(8)));
typedef unsigned int u32x4 __attribute__((ext_vector_type(4)));

static constexpr int MTOT = 16384;   // B*N
static constexpr int C = 768;
static constexpr int N3 = 2304;

DEVI unsigned short f2bf(float x) {
  unsigned int u = __builtin_bit_cast(unsigned int, x);
  return (unsigned short)((u + 0x7FFFu + ((u >> 16) & 1u)) >> 16);
}

DEVI f32x4 mfma16(s16x8 a, s16x8 b, f32x4 c) {
  return __builtin_amdgcn_mfma_f32_16x16x32_bf16(
      __builtin_bit_cast(b16x8, a), __builtin_bit_cast(b16x8, b), c, 0, 0, 0);
}

DEVI void async16(const void* g, void* l) {
  __builtin_amdgcn_global_load_lds(
      (__attribute__((address_space(1))) void*)g,
      (__attribute__((address_space(3))) void*)l, 16, 0, 0);
}

// ---------------- prep kernels ----------------

__global__ __launch_bounds__(256) void k_prep_x(const float* __restrict__ x,
                                                unsigned short* __restrict__ xb) {
  int idx = (blockIdx.x * 256 + threadIdx.x) * 4;
  float4 v = *(const float4*)(x + idx);
  uint2 p;
  p.x = (unsigned int)f2bf(v.x) | ((unsigned int)f2bf(v.y) << 16);
  p.y = (unsigned int)f2bf(v.z) | ((unsigned int)f2bf(v.w) << 16);
  *(uint2*)(xb + idx) = p;
}

__global__ __launch_bounds__(256) void k_prep_wqkv(
    const float* __restrict__ W, const float* __restrict__ Aq,
    const float* __restrict__ Bq, const float* __restrict__ Ak,
    const float* __restrict__ Bk, const float* __restrict__ Av,
    const float* __restrict__ Bv, unsigned short* __restrict__ out) {
  int idx = blockIdx.x * 256 + threadIdx.x;  // n*768 + c
  int n = idx / 768, c = idx - n * 768;
  int s = n / 768, co = n - s * 768;
  const float* A = (s == 0) ? Aq : (s == 1) ? Ak : Av;
  const float* Bm = (s == 0) ? Bq : (s == 1) ? Bk : Bv;
  float acc = W[idx];
#pragma unroll
  for (int r = 0; r < 16; ++r) acc += Bm[co * 16 + r] * A[r * 768 + c];
  out[idx] = f2bf(acc);
}

// M[r][j] = sum_c Ao[r][c] * Wp[c][j]
__global__ __launch_bounds__(256) void k_prep_M(const float* __restrict__ Ao,
                                                const float* __restrict__ Wp,
                                                float* __restrict__ M) {
  int r = blockIdx.x, t = threadIdx.x;
  float a0 = 0.f, a1 = 0.f, a2 = 0.f;
  for (int c = 0; c < 768; ++c) {
    float a = Ao[r * 768 + c];
    a0 += a * Wp[c * 768 + t];
    a1 += a * Wp[c * 768 + t + 256];
    a2 += a * Wp[c * 768 + t + 512];
  }
  M[r * 768 + t] = a0;
  M[r * 768 + t + 256] = a1;
  M[r * 768 + t + 512] = a2;
}

__global__ __launch_bounds__(256) void k_prep_wpe(const float* __restrict__ Wp,
                                                  const float* __restrict__ Bo,
                                                  const float* __restrict__ M,
                                                  unsigned short* __restrict__ out) {
  int idx = blockIdx.x * 256 + threadIdx.x;  // n*768 + j
  int n = idx / 768, j = idx - n * 768;
  float acc = Wp[idx];
#pragma unroll
  for (int r = 0; r < 16; ++r) acc += Bo[n * 16 + r] * M[r * 768 + j];
  out[idx] = f2bf(acc);
}

__global__ __launch_bounds__(256) void k_prep_beff(const float* __restrict__ bp,
                                                   const float* __restrict__ Ao,
                                                   const float* __restrict__ Bo,
                                                   float* __restrict__ beff) {
  __shared__ float bv[16];
  int t = threadIdx.x;
  if (t < 16) {
    float a0 = 0.f, a1 = 0.f, a2 = 0.f;
    for (int c = 0; c < 256; ++c) {
      a0 += Ao[t * 768 + c] * bp[c];
      a1 += Ao[t * 768 + c + 256] * bp[c + 256];
      a2 += Ao[t * 768 + c + 512] * bp[c + 512];
    }
    bv[t] = a0 + a1 + a2;
  }
  __syncthreads();
  int n = blockIdx.x * 256 + t;
  float acc = bp[n];
#pragma unroll
  for (int r = 0; r < 16; ++r) acc += Bo[n * 16 + r] * bv[r];
  beff[n] = acc;
}

// ---------------- QKV GEMM: [16384,768] x [2304,768]^T -> q/k/vt bf16 --------
// q: [bh][pos][64], pre-scaled by SCALE*log2e.  k: [bh][pos][64].
// vt: [bh][64][1024] (transposed per head), packed 8B stores.

__global__ __launch_bounds__(256) void k_gemm_qkv(
    const unsigned short* __restrict__ A, const unsigned short* __restrict__ Bw,
    const float* __restrict__ bias, unsigned short* __restrict__ qb,
    unsigned short* __restrict__ kb, unsigned short* __restrict__ vtb) {
  __shared__ short la[128 * 32];
  __shared__ short lb[128 * 32];
  const int t = threadIdx.x;
  const int w = t >> 6, l = t & 63;
  const int i = l & 15, qd = l >> 4;
  const int wm = w >> 1, wn = w & 1;
  const int mblk = blockIdx.x, nblk = blockIdx.y;

  const unsigned short* Ab = A + (size_t)(mblk * 128) * 768;
  const unsigned short* Bb = Bw + (size_t)(nblk * 128) * 768;
  const int sr = l >> 2;        // 0..15
  const int sc = (l & 3) * 8;   // 0,8,16,24

  f32x4 acc[4][4] = {};

  for (int kb_ = 0; kb_ < 24; ++kb_) {
    const int k0 = kb_ * 32;
#pragma unroll
    for (int j = 0; j < 2; ++j) {
      const int row = w * 32 + j * 16 + sr;
      async16(Ab + row * 768 + k0 + sc, &la[(w * 32 + j * 16) * 32]);
      async16(Bb + row * 768 + k0 + sc, &lb[(w * 32 + j * 16) * 32]);
    }
    __syncthreads();
    s16x8 af[4], bf[4];
#pragma unroll
    for (int mi = 0; mi < 4; ++mi)
      af[mi] = *(const s16x8*)&la[(wm * 64 + mi * 16 + i) * 32 + qd * 8];
#pragma unroll
    for (int ni = 0; ni < 4; ++ni)
      bf[ni] = *(const s16x8*)&lb[(wn * 64 + ni * 16 + i) * 32 + qd * 8];
#pragma unroll
    for (int mi = 0; mi < 4; ++mi)
#pragma unroll
      for (int ni = 0; ni < 4; ++ni)
        acc[mi][ni] = mfma16(af[mi], bf[ni], acc[mi][ni]);
    __syncthreads();
  }

  const float c1 = 0.18033688011112042f;  // SCALE * log2(e)
#pragma unroll
  for (int ni = 0; ni < 4; ++ni) {
    const int n = nblk * 128 + wn * 64 + ni * 16 + i;
    const int s = n / 768;
    const int nrel = n - s * 768;
    const int h = nrel >> 6, d = nrel & 63;
    const float bvv = bias[n];
    if (s == 2) {
      // V: transposed, packed 4x bf16 (r -> consecutive pos)
#pragma unroll
      for (int mi = 0; mi < 4; ++mi) {
        const int m0 = mblk * 128 + wm * 64 + mi * 16 + qd * 4;
        const int b = m0 >> 10, pos0 = m0 & 1023;
        uint2 pk;
        pk.x = (unsigned int)f2bf(acc[mi][ni][0] + bvv) |
               ((unsigned int)f2bf(acc[mi][ni][1] + bvv) << 16);
        pk.y = (unsigned int)f2bf(acc[mi][ni][2] + bvv) |
               ((unsigned int)f2bf(acc[mi][ni][3] + bvv) << 16);
        *(uint2*)&vtb[(size_t)((b * 12 + h) * 64 + d) * 1024 + pos0] = pk;
      }
    } else {
      unsigned short* dst = (s == 0) ? qb : kb;
      const float scl = (s == 0) ? c1 : 1.0f;
#pragma unroll
      for (int mi = 0; mi < 4; ++mi) {
#pragma unroll
        for (int r = 0; r < 4; ++r) {
          const int m = mblk * 128 + wm * 64 + mi * 16 + qd * 4 + r;
          const int b = m >> 10, pos = m & 1023;
          dst[(size_t)((b * 12 + h) * 1024 + pos) * 64 + d] =
              f2bf((acc[mi][ni][r] + bvv) * scl);
        }
      }
    }
  }
}

// ---------------- flash attention round 3 ----------------
// grid: (192 bh, 8 q-tiles of 128 rows), 256 threads (4 waves x 32 q-rows).
// P kept in registers (C-layout == half-K A-layout), l-sum via ones MFMA.

__global__ __launch_bounds__(256, 4) void k_attn(
    const unsigned short* __restrict__ qg, const unsigned short* __restrict__ kg,
    const unsigned short* __restrict__ vtg, unsigned short* __restrict__ og) {
  __shared__ short k_lds[2][64 * 64];
  __shared__ short vt_lds[2][64 * 64];

  const int t = threadIdx.x;
  const int w = t >> 6, l = t & 63;
  const int i = l & 15, qd = l >> 4;
  const int ix7 = l & 7;
  const int bh = blockIdx.x;    // 0..191 (fastest -> same-bh tiles share XCD)
  const int qblk = blockIdx.y;  // 0..7
  const int h = bh % 12, b = bh / 12;

  const unsigned short* Qg = qg + (size_t)(bh * 1024 + qblk * 128) * 64;
  const unsigned short* Kg = kg + (size_t)bh * 1024 * 64;
  const unsigned short* Vtg = vtg + (size_t)bh * 64 * 1024;

  // staging lane mapping (lane -> 16B LDS chunk, XOR swizzle on global side)
  const int srl = l >> 3;            // row-local 0..7
  const int sgc = (l & 7) ^ srl;     // swizzled global chunk 0..7

  // Q B-fragments direct from global: qf[nq][k0] = Q[w*32+nq*16+i][k0*32+qd*8..]
  s16x8 qf[2][2];
#pragma unroll
  for (int nq = 0; nq < 2; ++nq)
#pragma unroll
    for (int k0 = 0; k0 < 2; ++k0)
      qf[nq][k0] =
          *(const s16x8*)(Qg + (w * 32 + nq * 16 + i) * 64 + k0 * 32 + qd * 8);

  auto stage = [&](int bufn, int tkv) {
#pragma unroll
    for (int it = 0; it < 2; ++it) {
      const int rbase = it * 32 + w * 8;
      async16(Kg + (size_t)(tkv * 64 + rbase + srl) * 64 + sgc * 8,
              &k_lds[bufn][rbase * 64]);
      async16(Vtg + (size_t)(rbase + srl) * 1024 + tkv * 64 + sgc * 8,
              &vt_lds[bufn][rbase * 64]);
    }
  };

  stage(0, 0);

  f32x4 oacc[2][4] = {};  // [mq][nd], C-layout
  f32x4 lacc[2] = {};     // [mq], same C-layout rows as oacc
  const u32x4 ones_u = {0x3F803F80u, 0x3F803F80u, 0u, 0u};  // bf16 1.0 x4, hi 0
  const s16x8 ones = __builtin_bit_cast(s16x8, ones_u);

  for (int tkv = 0; tkv < 16; ++tkv) {
    const int buf = tkv & 1;
    __syncthreads();
    if (tkv < 15) stage(buf ^ 1, tkv + 1);

#pragma unroll
    for (int mi = 0; mi < 4; ++mi) {
      // GEMM1: S^T[pos][qrow] = K * Q^T  (full K=32 MFMAs)
      f32x4 st[2] = {};
#pragma unroll
      for (int k0 = 0; k0 < 2; ++k0) {
        const s16x8 kf = *(const s16x8*)&k_lds[buf][(mi * 16 + i) * 64 +
                                                    (((k0 * 4 + qd) ^ ix7) * 8)];
        st[0] = mfma16(kf, qf[0][k0], st[0]);
        st[1] = mfma16(kf, qf[1][k0], st[1]);
      }

      // exp2 (pre-scaled logits) + truncating pack into half-K A-frags
      s16x8 pa[2];
#pragma unroll
      for (int mq = 0; mq < 2; ++mq) {
        unsigned int u0 = __builtin_bit_cast(
            unsigned int, __builtin_amdgcn_exp2f(st[mq][0]));
        unsigned int u1 = __builtin_bit_cast(
            unsigned int, __builtin_amdgcn_exp2f(st[mq][1]));
        unsigned int u2 = __builtin_bit_cast(
            unsigned int, __builtin_amdgcn_exp2f(st[mq][2]));
        unsigned int u3 = __builtin_bit_cast(
            unsigned int, __builtin_amdgcn_exp2f(st[mq][3]));
        u32x4 p;
        p[0] = __builtin_amdgcn_perm(u1, u0, 0x07060302u);
        p[1] = __builtin_amdgcn_perm(u3, u2, 0x07060302u);
        p[2] = 0u;
        p[3] = 0u;
        pa[mq] = __builtin_bit_cast(s16x8, p);
      }

      // GEMM2 (half-K): O[qrow][d] += P[qrow][pos16(mi)] * V[pos][d]
#pragma unroll
      for (int nd = 0; nd < 4; ++nd) {
        const uint2 v = *(const uint2*)&vt_lds[buf][(nd * 16 + i) * 64 +
                                                    ((((mi * 2 + (qd >> 1)) ^ ix7) * 8) +
                                                     (qd & 1) * 4)];
        u32x4 vu = {v.x, v.y, 0u, 0u};
        const s16x8 vf = __builtin_bit_cast(s16x8, vu);
        oacc[0][nd] = mfma16(pa[0], vf, oacc[0][nd]);
        oacc[1][nd] = mfma16(pa[1], vf, oacc[1][nd]);
      }
      lacc[0] = mfma16(pa[0], ones, lacc[0]);
      lacc[1] = mfma16(pa[1], ones, lacc[1]);
    }
  }

  // epilogue: oacc and lacc share the same lane/reg layout -> no shuffles
  const int orow0 = qblk * 128 + w * 32;
#pragma unroll
  for (int mq = 0; mq < 2; ++mq) {
    float linv[4];
#pragma unroll
    for (int r = 0; r < 4; ++r) linv[r] = 1.0f / lacc[mq][r];
#pragma unroll
    for (int nd = 0; nd < 4; ++nd)
#pragma unroll
      for (int r = 0; r < 4; ++r) {
        const int pos = orow0 + mq * 16 + qd * 4 + r;
        const int d = nd * 16 + i;
        og[(size_t)(b * 1024 + pos) * 768 + h * 64 + d] =
            f2bf(oacc[mq][nd][r] * linv[r]);
      }
  }
}

// ---------------- proj GEMM: [16384,768] x [768,768]^T + b_eff -> f32 out ----

__global__ __launch_bounds__(256) void k_gemm_proj(
    const unsigned short* __restrict__ A, const unsigned short* __restrict__ Bw,
    const float* __restrict__ bias, float* __restrict__ out) {
  __shared__ short la[128 * 32];
  __shared__ short lb[128 * 32];
  const int t = threadIdx.x;
  const int w = t >> 6, l = t & 63;
  const int i = l & 15, qd = l >> 4;
  const int wm = w >> 1, wn = w & 1;
  const int mblk = blockIdx.x, nblk = blockIdx.y;

  const unsigned short* Ab = A + (size_t)(mblk * 128) * 768;
  const unsigned short* Bb = Bw + (size_t)(nblk * 128) * 768;
  const int sr = l >> 2;
  const int sc = (l & 3) * 8;

  f32x4 acc[4][4] = {};

  for (int kb_ = 0; kb_ < 24; ++kb_) {
    const int k0 = kb_ * 32;
#pragma unroll
    for (int j = 0; j < 2; ++j) {
      const int row = w * 32 + j * 16 + sr;
      async16(Ab + row * 768 + k0 + sc, &la[(w * 32 + j * 16) * 32]);
      async16(Bb + row * 768 + k0 + sc, &lb[(w * 32 + j * 16) * 32]);
    }
    __syncthreads();
    s16x8 af[4], bf[4];
#pragma unroll
    for (int mi = 0; mi < 4; ++mi)
      af[mi] = *(const s16x8*)&la[(wm * 64 + mi * 16 + i) * 32 + qd * 8];
#pragma unroll
    for (int ni = 0; ni < 4; ++ni)
      bf[ni] = *(const s16x8*)&lb[(wn * 64 + ni * 16 + i) * 32 + qd * 8];
#pragma unroll
    for (int mi = 0; mi < 4; ++mi)
#pragma unroll
      for (int ni = 0; ni < 4; ++ni)
        acc[mi][ni] = mfma16(af[mi], bf[ni], acc[mi][ni]);
    __syncthreads();
  }

#pragma unroll
  for (int ni = 0; ni < 4; ++ni) {
    const int n = nblk * 128 + wn * 64 + ni * 16 + i;
    const float bvv = bias[n];
#pragma unroll
    for (int mi = 0; mi < 4; ++mi) {
#pragma unroll
      for (int r = 0; r < 4; ++r) {
        const int m = mblk * 128 + wm * 64 + mi * 16 + qd * 4 + r;
        out[(size_t)m * 768 + n] = acc[mi][ni][r] + bvv;
      }
    }
  }
}

// ---------------- host ----------------

extern "C" void kernel_launch(void* const* d_in, const int* in_sizes, int n_in,
                              void* d_out, int out_size, void* d_ws, size_t ws_size,
                              hipStream_t stream) {
  const float* x = (const float*)d_in[0];
  const float* Wqkv = (const float*)d_in[1];
  const float* bqkv = (const float*)d_in[2];
  const float* Wp = (const float*)d_in[3];
  const float* bp = (const float*)d_in[4];
  const float* Aq = (const float*)d_in[5];
  const float* Bq = (const float*)d_in[6];
  const float* Ak = (const float*)d_in[7];
  const float* Bk = (const float*)d_in[8];
  const float* Av = (const float*)d_in[9];
  const float* Bv = (const float*)d_in[10];
  const float* Ao = (const float*)d_in[11];
  const float* Bo = (const float*)d_in[12];
  float* out = (float*)d_out;

  unsigned short* xb = (unsigned short*)d_ws;         // 16384*768
  unsigned short* wqkvb = xb + (size_t)MTOT * C;      // 2304*768
  unsigned short* wpeb = wqkvb + (size_t)N3 * C;      // 768*768
  unsigned short* qb = wpeb + (size_t)C * C;          // 192*1024*64
  unsigned short* kb = qb + (size_t)MTOT * C;
  unsigned short* vtb = kb + (size_t)MTOT * C;        // 192*64*1024 (transposed)
  float* Mbuf = (float*)(vtb + (size_t)MTOT * C);     // 16*768
  float* beff = Mbuf + 16 * 768;                      // 768
  unsigned short* ob = xb;  // alias: xb dead after k_gemm_qkv

  k_prep_x<<<12288, 256, 0, stream>>>(x, xb);
  k_prep_wqkv<<<6912, 256, 0, stream>>>(Wqkv, Aq, Bq, Ak, Bk, Av, Bv, wqkvb);
  k_prep_M<<<16, 256, 0, stream>>>(Ao, Wp, Mbuf);
  k_prep_wpe<<<2304, 256, 0, stream>>>(Wp, Bo, Mbuf, wpeb);
  k_prep_beff<<<3, 256, 0, stream>>>(bp, Ao, Bo, beff);

  k_gemm_qkv<<<dim3(128, 18), 256, 0, stream>>>(xb, wqkvb, bqkv, qb, kb, vtb);
  k_attn<<<dim3(192, 8), 256, 0, stream>>>(qb, kb, vtb, ob);
  k_gemm_proj<<<dim3(128, 6), 256, 0, stream>>>(ob, wpeb, beff, out);
}